// Round 8
// baseline (412.804 us; speedup 1.0000x reference)
//
#include <hip/hip_runtime.h>

typedef unsigned int uint32;
typedef unsigned short ushort16;

typedef __attribute__((ext_vector_type(8))) short short8;
typedef __attribute__((ext_vector_type(4))) float f32x4;
typedef __attribute__((ext_vector_type(4))) int i32x4;
typedef __attribute__((ext_vector_type(2))) uint32 u32x2;
typedef __attribute__((ext_vector_type(4))) uint32 u32x4;

// ---------------------------------------------------------------------------
// GNN: h1 = relu((x + mean_agg(x)) @ W1 + b1)
//      h2 = relu((h1 + mean_agg(h1)) @ W2 + b2)
//      out = h2 @ Wp + bp
//
// R18: consolidate prep to 2 stages + nontemporal output discipline.
//  R17 post-mortem (325us): agg regressed 63->76us (fetch 3.0->2.5 TB/s,
//  WRITE 25->2.4MB) — producer kernels leave ~33MB dirty in 32MB aggregate
//  L2 right before the gather; every gather miss pays a dirty-victim
//  writeback. Fix: nt-stores on ALL producer outputs (flushed to L3 at
//  kernel end anyway), nt-loads on read-once streams.
//  Prep: count/scan/scatter merged into ONE kernel: LDS count own chunk ->
//  atomicAdd(&rcursor[r],cnt[r]) range reservation -> scatter into own
//  ranges. Regions 1024 nodes (R=98, rlist 19MB, csr window 65KB).
//  Pipeline: K1 partition+Wtprep | K2 csr(98)||GEMM1(391) @1024t |
//            K3 agg1 | K4 gemm2 | K5 agg2+proj.
// R19: fix compile — __builtin_nontemporal_* requires ext_vector types,
//  not HIP_vector_type (int4/uint2/float4). Same semantics via i32x4 etc.
// ---------------------------------------------------------------------------

#define RSH 10                 // 1024 nodes per region
#define NRG 1024               // nodes per region
#define CAP 24576              // rlist capacity per region (avg 16.3K, +65 sigma)
#define CH  2048               // edges per partition block

__device__ __forceinline__ ushort16 f2bf(float f) {
    uint32 u = __float_as_uint(f);
    u += 0x7fffu + ((u >> 16) & 1u);       // round-to-nearest-even
    return (ushort16)(u >> 16);
}
__device__ __forceinline__ float bfhi(uint32 u) { return __uint_as_float(u & 0xffff0000u); }
__device__ __forceinline__ float bflo(uint32 u) { return __uint_as_float(u << 16); }
__device__ __forceinline__ uint32 pack2(float a, float b) {
    return (uint32)f2bf(a) | ((uint32)f2bf(b) << 16);
}

union U16 { uint4 u; short8 s; };
__device__ __forceinline__ short8 ld_frag(const ushort16* p) {
    U16 x; x.u = *(const uint4*)p; return x.s;
}
union U16NT { u32x4 u; short8 s; };
__device__ __forceinline__ short8 ld_frag_nt(const ushort16* p) {
    U16NT x; x.u = __builtin_nontemporal_load((const u32x4*)p); return x.s;
}

#define ACC8(v) \
    acc[0] += bflo(v.x); acc[1] += bfhi(v.x); \
    acc[2] += bflo(v.y); acc[3] += bfhi(v.y); \
    acc[4] += bflo(v.z); acc[5] += bfhi(v.z); \
    acc[6] += bflo(v.w); acc[7] += bfhi(v.w);

// ---------------------------------------------------------------------------
// K1: per-chunk count -> global range reservation -> scatter into own ranges.
//     + Wt prep on 16 extra blocks.
// ---------------------------------------------------------------------------
__global__ __launch_bounds__(256)
void partition_prep_kernel(const int* __restrict__ src, const int* __restrict__ tgt,
                           uint2* __restrict__ rlist, int* __restrict__ rcursor,
                           const float* __restrict__ W1, const float* __restrict__ W2,
                           ushort16* __restrict__ Wt1, ushort16* __restrict__ Wt2,
                           int E, int PB, int R) {
    int tid = threadIdx.x, blk = blockIdx.x;
    if (blk >= PB) {   // Wt prep: 16 blocks, 2048 floats each, float4 loads
        int idx = blk - PB;
        const float* W = (idx >> 3) ? W2 : W1;
        ushort16* Wt = (idx >> 3) ? Wt2 : Wt1;
        int i0 = (idx & 7) * 2048 + tid * 8;
        float4 a = *(const float4*)(W + i0);
        float4 b = *(const float4*)(W + i0 + 4);
        int k = i0 >> 7, col = i0 & 127;
        Wt[(col + 0) * 128 + k] = f2bf(a.x);
        Wt[(col + 1) * 128 + k] = f2bf(a.y);
        Wt[(col + 2) * 128 + k] = f2bf(a.z);
        Wt[(col + 3) * 128 + k] = f2bf(a.w);
        Wt[(col + 4) * 128 + k] = f2bf(b.x);
        Wt[(col + 5) * 128 + k] = f2bf(b.y);
        Wt[(col + 6) * 128 + k] = f2bf(b.z);
        Wt[(col + 7) * 128 + k] = f2bf(b.w);
        return;
    }
    __shared__ int cnt[128];
    __shared__ int cbase[128];
    if (tid < 128) cnt[tid] = 0;
    __syncthreads();
    int q0 = blk * (CH / 4), q1 = min(q0 + CH / 4, E / 4);
    // pass 1: count own chunk
    for (int q = q0 + tid; q < q1; q += 256) {
        i32x4 t = __builtin_nontemporal_load((const i32x4*)tgt + q);
        atomicAdd(&cnt[t.x >> RSH], 1);
        atomicAdd(&cnt[t.y >> RSH], 1);
        atomicAdd(&cnt[t.z >> RSH], 1);
        atomicAdd(&cnt[t.w >> RSH], 1);
    }
    if (blk == 0 && tid == 0)
        for (int e = (E / 4) * 4; e < E; ++e) atomicAdd(&cnt[tgt[e] >> RSH], 1);
    __syncthreads();
    // reserve contiguous ranges (one parallel atomic round; totals determin.)
    if (tid < R) cbase[tid] = atomicAdd(&rcursor[tid], cnt[tid]);
    __syncthreads();
    if (tid < 128) cnt[tid] = 0;   // reuse as local cursor
    __syncthreads();
    // pass 2: scatter into own reserved ranges (write-local, full lines)
    for (int q = q0 + tid; q < q1; q += 256) {
        i32x4 t = __builtin_nontemporal_load((const i32x4*)tgt + q);
        i32x4 s = __builtin_nontemporal_load((const i32x4*)src + q);
        int r0 = t.x >> RSH, r1 = t.y >> RSH, r2 = t.z >> RSH, r3 = t.w >> RSH;
        int p0 = cbase[r0] + atomicAdd(&cnt[r0], 1);
        int p1 = cbase[r1] + atomicAdd(&cnt[r1], 1);
        int p2 = cbase[r2] + atomicAdd(&cnt[r2], 1);
        int p3 = cbase[r3] + atomicAdd(&cnt[r3], 1);
        u32x2 e0; e0.x = (uint32)s.x; e0.y = (uint32)t.x;
        u32x2 e1; e1.x = (uint32)s.y; e1.y = (uint32)t.y;
        u32x2 e2; e2.x = (uint32)s.z; e2.y = (uint32)t.z;
        u32x2 e3; e3.x = (uint32)s.w; e3.y = (uint32)t.w;
        if (p0 < CAP) __builtin_nontemporal_store(e0, (u32x2*)&rlist[(size_t)r0 * CAP + p0]);
        if (p1 < CAP) __builtin_nontemporal_store(e1, (u32x2*)&rlist[(size_t)r1 * CAP + p1]);
        if (p2 < CAP) __builtin_nontemporal_store(e2, (u32x2*)&rlist[(size_t)r2 * CAP + p2]);
        if (p3 < CAP) __builtin_nontemporal_store(e3, (u32x2*)&rlist[(size_t)r3 * CAP + p3]);
    }
    if (blk == 0 && tid == 0) {
        for (int e = (E / 4) * 4; e < E; ++e) {
            int t = tgt[e], r = t >> RSH;
            int p = cbase[r] + atomicAdd(&cnt[r], 1);
            if (p < CAP) rlist[(size_t)r * CAP + p] = make_uint2((uint32)src[e], (uint32)t);
        }
    }
}

// ---------------------------------------------------------------------------
// GEMM per-wave body: 16 rows x 128 cols at row base r0w; nt in/out.
// INF32: A f32 (in-register bf16 cvt); else A bf16 row-major.
// ---------------------------------------------------------------------------
template<int INF32>
__device__ __forceinline__
void gemm_rows(const void* __restrict__ Asrc, const ushort16* __restrict__ Wt,
               int M, ushort16* __restrict__ outB, int r0w) {
    const int lane = threadIdx.x & 63;
    const int l15 = lane & 15;
    const int quad = lane >> 4;

    int arow = r0w + l15;
    if (arow >= M) arow = M - 1;

    short8 afr[4];
    if (INF32) {
        const float* ap = (const float*)Asrc + (size_t)arow * 128 + quad * 8;
#pragma unroll
        for (int kt = 0; kt < 4; ++kt) {
            f32x4 a0 = __builtin_nontemporal_load((const f32x4*)(ap + kt * 32));
            f32x4 a1 = __builtin_nontemporal_load((const f32x4*)(ap + kt * 32 + 4));
            short8 f;
            f[0] = (short)f2bf(a0.x); f[1] = (short)f2bf(a0.y);
            f[2] = (short)f2bf(a0.z); f[3] = (short)f2bf(a0.w);
            f[4] = (short)f2bf(a1.x); f[5] = (short)f2bf(a1.y);
            f[6] = (short)f2bf(a1.z); f[7] = (short)f2bf(a1.w);
            afr[kt] = f;
        }
    } else {
        const ushort16* aptr = (const ushort16*)Asrc + (size_t)arow * 128 + quad * 8;
#pragma unroll
        for (int kt = 0; kt < 4; ++kt) afr[kt] = ld_frag_nt(aptr + kt * 32);
    }

    f32x4 acc[8];
#pragma unroll
    for (int t = 0; t < 8; ++t) acc[t] = (f32x4){0.f, 0.f, 0.f, 0.f};

#pragma unroll
    for (int t = 0; t < 8; ++t) {
        const ushort16* bptr = Wt + (size_t)(16 * t + l15) * 128 + quad * 8;
        short8 b0 = ld_frag(bptr);
        short8 b1 = ld_frag(bptr + 32);
        short8 b2 = ld_frag(bptr + 64);
        short8 b3 = ld_frag(bptr + 96);
        acc[t] = __builtin_amdgcn_mfma_f32_16x16x32_bf16(afr[0], b0, acc[t], 0, 0, 0);
        acc[t] = __builtin_amdgcn_mfma_f32_16x16x32_bf16(afr[1], b1, acc[t], 0, 0, 0);
        acc[t] = __builtin_amdgcn_mfma_f32_16x16x32_bf16(afr[2], b2, acc[t], 0, 0, 0);
        acc[t] = __builtin_amdgcn_mfma_f32_16x16x32_bf16(afr[3], b3, acc[t], 0, 0, 0);
    }

#pragma unroll
    for (int t = 0; t < 8; ++t) {
        float ov[4];
        ov[0] = acc[t].x; ov[1] = acc[t].y; ov[2] = acc[t].z; ov[3] = acc[t].w;
#pragma unroll
        for (int r = 0; r < 4; ++r) {
            float nb = __shfl_xor(ov[r], 1, 64);
            int row = r0w + quad * 4 + r;
            if (((l15 & 1) == 0) && row < M) {
                __builtin_nontemporal_store(pack2(ov[r], nb),
                    (uint32*)(outB + (size_t)row * 128 + 16 * t + l15));
            }
        }
    }
}

// ---------------------------------------------------------------------------
// K2 (1024 threads): blocks < R: region CSR build; blocks >= R: GEMM1.
// ---------------------------------------------------------------------------
__global__ __launch_bounds__(1024)
void csr_gemm1_kernel(const uint2* __restrict__ rlist, const int* __restrict__ rcursor,
                      int* __restrict__ start, int* __restrict__ deg,
                      int* __restrict__ csr, int N, int R,
                      const float* __restrict__ x, const ushort16* __restrict__ Wt1,
                      ushort16* __restrict__ ybuf) {
    int blk = blockIdx.x;
    int tid = threadIdx.x;
    if (blk >= R) {
        int gid = blk - R;
        gemm_rows<1>(x, Wt1, N, ybuf, gid * 256 + (tid >> 6) * 16);
        return;
    }
    __shared__ int hist[NRG];
    __shared__ int sd[1024];
    __shared__ int rbaseSh, countSh;

    int r = blk;
    // prefix over region totals (deterministic counts)
    if (tid < 128) sd[tid] = (tid < R) ? rcursor[tid] : 0;
    __syncthreads();
    for (int o = 1; o < 128; o <<= 1) {
        int t = (tid >= o && tid < 128) ? sd[tid - o] : 0;
        __syncthreads();
        if (tid < 128) sd[tid] += t;
        __syncthreads();
    }
    if (tid == 0) {
        int incl = sd[r];
        int excl = (r == 0) ? 0 : sd[r - 1];
        rbaseSh = excl;
        countSh = min(incl - excl, CAP);
    }
    hist[tid] = 0;
    __syncthreads();
    int count = countSh;
    const u32x2* rl = (const u32x2*)(rlist + (size_t)r * CAP);
    int n0 = r << RSH;

    // pass 1: degree histogram, 4x unrolled
    {
        int i = tid;
        for (; i + 3072 < count; i += 4096) {
            u32x2 a = __builtin_nontemporal_load(rl + i);
            u32x2 b = __builtin_nontemporal_load(rl + i + 1024);
            u32x2 c = __builtin_nontemporal_load(rl + i + 2048);
            u32x2 d = __builtin_nontemporal_load(rl + i + 3072);
            atomicAdd(&hist[a.y & (NRG - 1)], 1);
            atomicAdd(&hist[b.y & (NRG - 1)], 1);
            atomicAdd(&hist[c.y & (NRG - 1)], 1);
            atomicAdd(&hist[d.y & (NRG - 1)], 1);
        }
        for (; i < count; i += 1024) {
            u32x2 e = __builtin_nontemporal_load(rl + i);
            atomicAdd(&hist[e.y & (NRG - 1)], 1);
        }
    }
    __syncthreads();

    // exclusive scan of 1024; emit start/deg; hist -> cursor
    {
        int v = hist[tid];
        sd[tid] = v;
        __syncthreads();
        for (int o = 1; o < 1024; o <<= 1) {
            int t = (tid >= o) ? sd[tid - o] : 0;
            __syncthreads();
            sd[tid] += t;
            __syncthreads();
        }
        int excl = sd[tid] - v + rbaseSh;
        int node = n0 + tid;
        if (node < N) { start[node] = excl; deg[node] = v; }
        hist[tid] = excl;   // becomes scatter cursor
        __syncthreads();
    }

    // pass 2: scatter into own csr window (~65KB, L2-resident), 4x unrolled
    {
        int i = tid;
        for (; i + 3072 < count; i += 4096) {
            u32x2 a = __builtin_nontemporal_load(rl + i);
            u32x2 b = __builtin_nontemporal_load(rl + i + 1024);
            u32x2 c = __builtin_nontemporal_load(rl + i + 2048);
            u32x2 d = __builtin_nontemporal_load(rl + i + 3072);
            int pa = atomicAdd(&hist[a.y & (NRG - 1)], 1);
            int pb = atomicAdd(&hist[b.y & (NRG - 1)], 1);
            int pc = atomicAdd(&hist[c.y & (NRG - 1)], 1);
            int pd = atomicAdd(&hist[d.y & (NRG - 1)], 1);
            __builtin_nontemporal_store((int)a.x, &csr[pa]);
            __builtin_nontemporal_store((int)b.x, &csr[pb]);
            __builtin_nontemporal_store((int)c.x, &csr[pc]);
            __builtin_nontemporal_store((int)d.x, &csr[pd]);
        }
        for (; i < count; i += 1024) {
            u32x2 e = __builtin_nontemporal_load(rl + i);
            int p = atomicAdd(&hist[e.y & (NRG - 1)], 1);
            __builtin_nontemporal_store((int)e.x, &csr[p]);
        }
    }
}

// standalone GEMM (layer 2), 256 threads
template<int INF32>
__global__ __launch_bounds__(256)
void gemm_raw_kernel(const void* __restrict__ Asrc, const ushort16* __restrict__ Wt,
                     int M, ushort16* __restrict__ outB) {
    gemm_rows<INF32>(Asrc, Wt, M, outB, blockIdx.x * 64 + (threadIdx.x >> 6) * 16);
}

// ---------------------------------------------------------------------------
// agg + epilogue: h = relu(in_t + mean_{s in N(t)} in_s + bias)
// PROJ=0: write h bf16 row-major (nt).  PROJ=1: out = h @ Wp + bp (f32).
// One wave per node; 8 edges in flight.
// ---------------------------------------------------------------------------
template<int PROJ>
__global__ __launch_bounds__(256, 4)
void agg_fuse_kernel(const ushort16* __restrict__ hb,
                     const int* __restrict__ start, const int* __restrict__ degv,
                     const int* __restrict__ csr,
                     const float* __restrict__ bias,
                     uint32* __restrict__ outb,
                     const float* __restrict__ Wp, const float* __restrict__ bp,
                     float* __restrict__ outP, int N) {
    int wid = (blockIdx.x * 256 + threadIdx.x) >> 6;
    int lane = threadIdx.x & 63;
    if (wid >= N) return;
    int g = lane >> 4, sl = lane & 15;
    int s0 = start[wid];
    int deg = degv[wid];
    int fi = sl * 4 + g;
    uint32 su = ((const uint32*)hb)[(size_t)wid * 64 + fi];

    float acc[8];
#pragma unroll
    for (int j = 0; j < 8; ++j) acc[j] = 0.f;

    int base = 0;
    for (; base + 8 <= deg; base += 8) {
        int i0 = csr[s0 + base + g];
        int i1 = csr[s0 + base + 4 + g];
        uint4 v0 = *(const uint4*)(hb + (size_t)i0 * 128 + sl * 8);
        uint4 v1 = *(const uint4*)(hb + (size_t)i1 * 128 + sl * 8);
        ACC8(v0); ACC8(v1);
    }
    for (; base < deg; base += 4) {
        int e = base + g;
        if (e < deg) {
            int s = csr[s0 + e];
            uint4 v = *(const uint4*)(hb + (size_t)s * 128 + sl * 8);
            ACC8(v);
        }
    }
#pragma unroll
    for (int j = 0; j < 8; ++j) {
        acc[j] += __shfl_xor(acc[j], 16, 64);
        acc[j] += __shfl_xor(acc[j], 32, 64);
    }
    float inv = 1.f / fmaxf((float)deg, 1.f);
    float ax = (g == 0) ? acc[0] : (g == 1) ? acc[2] : (g == 2) ? acc[4] : acc[6];
    float ay = (g == 0) ? acc[1] : (g == 1) ? acc[3] : (g == 2) ? acc[5] : acc[7];

    float ha = fmaxf(bflo(su) + ax * inv + bias[2 * fi],     0.f);
    float hc = fmaxf(bfhi(su) + ay * inv + bias[2 * fi + 1], 0.f);

    if (!PROJ) {
        __builtin_nontemporal_store(pack2(ha, hc), &outb[(size_t)wid * 64 + fi]);
    } else {
        float p[5];
#pragma unroll
        for (int j = 0; j < 5; ++j)
            p[j] = ha * Wp[(2 * fi) * 5 + j] + hc * Wp[(2 * fi + 1) * 5 + j];
#pragma unroll
        for (int m = 1; m <= 32; m <<= 1)
#pragma unroll
            for (int j = 0; j < 5; ++j) p[j] += __shfl_xor(p[j], m, 64);
        if (lane == 0) {
#pragma unroll
            for (int j = 0; j < 5; ++j)
                __builtin_nontemporal_store(p[j] + bp[j], &outP[(size_t)wid * 5 + j]);
        }
    }
}

extern "C" void kernel_launch(void* const* d_in, const int* in_sizes, int n_in,
                              void* d_out, int out_size, void* d_ws, size_t ws_size,
                              hipStream_t stream) {
    const float* x     = (const float*)d_in[0];
    const int*   edges = (const int*)d_in[1];
    const float* W1    = (const float*)d_in[2];
    const float* b1    = (const float*)d_in[3];
    const float* W2    = (const float*)d_in[4];
    const float* b2    = (const float*)d_in[5];
    const float* Wp    = (const float*)d_in[6];
    const float* bp    = (const float*)d_in[7];
    float* out = (float*)d_out;

    int N = in_sizes[0] / 128;   // 100000
    int E = in_sizes[1] / 2;     // 1600000
    const int* src = edges;
    const int* tgt = edges + E;

    const int R  = (N + NRG - 1) >> RSH;     // regions (98)
    const int PB = (E + CH - 1) / CH;        // partition blocks (782)

    char* ws = (char*)d_ws;
    size_t off = 0;
    auto alloc = [&](size_t bytes) {
        char* p = ws + off;
        off = (off + bytes + 255) & ~(size_t)255;
        return p;
    };
    int*      deg     = (int*)alloc((size_t)N * 4);
    int*      start   = (int*)alloc((size_t)N * 4);
    int*      csr     = (int*)alloc((size_t)E * 4);
    uint2*    rlist   = (uint2*)alloc((size_t)R * CAP * 8);
    int*      rcursor = (int*)alloc(128 * 4);
    ushort16* ybuf    = (ushort16*)alloc((size_t)N * 128 * 2);  // y, later z
    ushort16* h1      = (ushort16*)alloc((size_t)N * 128 * 2);
    ushort16* Wt1     = (ushort16*)alloc(128 * 128 * 2);
    ushort16* Wt2     = (ushort16*)alloc(128 * 128 * 2);
    (void)ws_size;

    const int g1Blocks   = (N + 255) / 256;      // 391 (1024-thr blocks)
    const int gemmBlocks = (N + 63) / 64;        // 1563
    const int aggBlocks  = (N + 3) / 4;          // 25000

    (void)hipMemsetAsync(rcursor, 0, 128 * 4, stream);
    // K1: count + reserve + scatter into region lists; Wt prep (16 blocks)
    partition_prep_kernel<<<PB + 16, 256, 0, stream>>>(src, tgt, rlist, rcursor,
                                                       W1, W2, Wt1, Wt2, E, PB, R);
    // K2: per-region CSR build (98 blocks)  ||  y = x @ W1 (391 blocks)
    csr_gemm1_kernel<<<R + g1Blocks, 1024, 0, stream>>>(rlist, rcursor, start, deg,
                                                        csr, N, R, x, Wt1, ybuf);
    // K3: h1 = relu(y + agg(y) + b1)
    agg_fuse_kernel<0><<<aggBlocks, 256, 0, stream>>>(ybuf, start, deg, csr, b1,
                                                      (uint32*)h1, nullptr, nullptr,
                                                      nullptr, N);
    // K4: z = h1 @ W2 (bf16 in, bf16 out, reuse ybuf)
    gemm_raw_kernel<0><<<gemmBlocks, 256, 0, stream>>>(h1, Wt2, N, ybuf);
    // K5: h2 = relu(z + agg(z) + b2); out = h2 @ Wp + bp
    agg_fuse_kernel<1><<<aggBlocks, 256, 0, stream>>>(ybuf, start, deg, csr, b2,
                                                      nullptr, Wp, bp, out, N);
}

// Round 9
// 332.533 us; speedup vs baseline: 1.2414x; 1.2414x over previous
//
#include <hip/hip_runtime.h>

typedef unsigned int uint32;
typedef unsigned short ushort16;

typedef __attribute__((ext_vector_type(8))) short short8;
typedef __attribute__((ext_vector_type(4))) float f32x4;

// ---------------------------------------------------------------------------
// GNN: h1 = relu((x + mean_agg(x)) @ W1 + b1)
//      h2 = relu((h1 + mean_agg(h1)) @ W2 + b2)
//      out = h2 @ Wp + bp
//
// R20: A/B rollback. R18 post-mortem: (1) nt-stores on scattered writes ->
//  WRITE 116MB (bypass L2 coalescing) — ALL nt removed. (2) dirty-L2 theory
//  of agg 63->76 regression FALSIFIED (R11 agg2 also read fresh GEMM output
//  at 63us). Remaining candidates: fused epilogue/commute vs csr machinery.
//  This round isolates: R11 compute path VERBATIM (cvt x->bf16; agg = pure
//  combine; bias+relu in GEMM epilogue; proj in gemm2) + R17-measured prep
//  (count/scan/scatter hist pipeline, no global atomics, regular stores),
//  regions shrunk to 512 nodes (R=196: more blocks, 33KB csr windows),
//  region-CSR passes 8x unrolled @512thr, cvt fused as filler blocks.
//  Merged-K1 (R18) dropped: 98-counter rcursor reservation ping-ponged one
//  line across 8 XCDs 76K times.
// ---------------------------------------------------------------------------

#define RSH 9                  // 512 nodes per region
#define NRG 512                // nodes per region
#define CAP 12288              // rlist capacity per region (avg 8.2K, +45 sigma)
#define CH  2048               // edges per count/scatter block

__device__ __forceinline__ ushort16 f2bf(float f) {
    uint32 u = __float_as_uint(f);
    u += 0x7fffu + ((u >> 16) & 1u);       // round-to-nearest-even
    return (ushort16)(u >> 16);
}
__device__ __forceinline__ float bfhi(uint32 u) { return __uint_as_float(u & 0xffff0000u); }
__device__ __forceinline__ float bflo(uint32 u) { return __uint_as_float(u << 16); }
__device__ __forceinline__ uint32 pack2(float a, float b) {
    return (uint32)f2bf(a) | ((uint32)f2bf(b) << 16);
}

union U16 { uint4 u; short8 s; };
__device__ __forceinline__ short8 ld_frag(const ushort16* p) {
    U16 x; x.u = *(const uint4*)p; return x.s;
}

#define ACC8(v) \
    acc[0] += bflo(v.x); acc[1] += bfhi(v.x); \
    acc[2] += bflo(v.y); acc[3] += bfhi(v.y); \
    acc[4] += bflo(v.z); acc[5] += bfhi(v.z); \
    acc[6] += bflo(v.w); acc[7] += bfhi(v.w);

// ---------------------------------------------------------------------------
// K1a: per-block region count (LDS only) + Wt prep on 16 extra blocks.
// ---------------------------------------------------------------------------
__global__ __launch_bounds__(256)
void count_prep_kernel(const int* __restrict__ tgt, int* __restrict__ hist,
                       const float* __restrict__ W1, const float* __restrict__ W2,
                       ushort16* __restrict__ Wt1, ushort16* __restrict__ Wt2,
                       int E, int PB) {
    int tid = threadIdx.x, blk = blockIdx.x;
    if (blk >= PB) {   // Wt prep: 16 blocks, 2048 floats each
        int idx = blk - PB;
        const float* W = (idx >> 3) ? W2 : W1;
        ushort16* Wt = (idx >> 3) ? Wt2 : Wt1;
        int i0 = (idx & 7) * 2048 + tid * 8;
        float4 a = *(const float4*)(W + i0);
        float4 b = *(const float4*)(W + i0 + 4);
        int k = i0 >> 7, col = i0 & 127;
        Wt[(col + 0) * 128 + k] = f2bf(a.x);
        Wt[(col + 1) * 128 + k] = f2bf(a.y);
        Wt[(col + 2) * 128 + k] = f2bf(a.z);
        Wt[(col + 3) * 128 + k] = f2bf(a.w);
        Wt[(col + 4) * 128 + k] = f2bf(b.x);
        Wt[(col + 5) * 128 + k] = f2bf(b.y);
        Wt[(col + 6) * 128 + k] = f2bf(b.z);
        Wt[(col + 7) * 128 + k] = f2bf(b.w);
        return;
    }
    __shared__ int cnt[256];
    cnt[tid] = 0;
    __syncthreads();
    int q0 = blk * (CH / 4), q1 = min(q0 + CH / 4, E / 4);
    for (int q = q0 + tid; q < q1; q += 256) {
        int4 t = ((const int4*)tgt)[q];
        atomicAdd(&cnt[t.x >> RSH], 1);
        atomicAdd(&cnt[t.y >> RSH], 1);
        atomicAdd(&cnt[t.z >> RSH], 1);
        atomicAdd(&cnt[t.w >> RSH], 1);
    }
    if (blk == 0 && tid == 0)
        for (int e = (E / 4) * 4; e < E; ++e) atomicAdd(&cnt[tgt[e] >> RSH], 1);
    __syncthreads();
    hist[(size_t)blk * 256 + tid] = cnt[tid];
}

// ---------------------------------------------------------------------------
// K1b: per-region exclusive column scan of hist over PB blocks + total[r].
// ---------------------------------------------------------------------------
__global__ __launch_bounds__(256)
void scan_kernel(int* __restrict__ hist, int* __restrict__ total, int PB) {
    __shared__ int sd[256];
    __shared__ int carrySh;
    int r = blockIdx.x, tid = threadIdx.x;
    if (tid == 0) carrySh = 0;
    __syncthreads();
    int chunks = (PB + 255) >> 8;
    for (int ch = 0; ch < chunks; ++ch) {
        int g = ch * 256 + tid;
        int v = (g < PB) ? hist[(size_t)g * 256 + r] : 0;
        int c0 = carrySh;
        sd[tid] = v;
        __syncthreads();
        for (int o = 1; o < 256; o <<= 1) {
            int t = (tid >= o) ? sd[tid - o] : 0;
            __syncthreads();
            sd[tid] += t;
            __syncthreads();
        }
        if (g < PB) hist[(size_t)g * 256 + r] = sd[tid] - v + c0;
        int tot = sd[255];
        __syncthreads();
        if (tid == 0) carrySh = c0 + tot;
        __syncthreads();
    }
    if (tid == 0) total[r] = carrySh;
}

// ---------------------------------------------------------------------------
// K1c: scatter (src,tgt) into reserved per-block ranges of per-region lists.
// ---------------------------------------------------------------------------
__global__ __launch_bounds__(256)
void scatter_kernel(const int* __restrict__ src, const int* __restrict__ tgt,
                    const int* __restrict__ hist, uint2* __restrict__ rlist,
                    int E) {
    __shared__ int cb[256];
    __shared__ int cnt[256];
    int tid = threadIdx.x, blk = blockIdx.x;
    cnt[tid] = 0;
    cb[tid] = hist[(size_t)blk * 256 + tid];
    __syncthreads();
    int q0 = blk * (CH / 4), q1 = min(q0 + CH / 4, E / 4);
    for (int q = q0 + tid; q < q1; q += 256) {
        int4 t = ((const int4*)tgt)[q];
        int4 s = ((const int4*)src)[q];
        int r0 = t.x >> RSH, r1 = t.y >> RSH, r2 = t.z >> RSH, r3 = t.w >> RSH;
        int p0 = cb[r0] + atomicAdd(&cnt[r0], 1);
        int p1 = cb[r1] + atomicAdd(&cnt[r1], 1);
        int p2 = cb[r2] + atomicAdd(&cnt[r2], 1);
        int p3 = cb[r3] + atomicAdd(&cnt[r3], 1);
        if (p0 < CAP) rlist[(size_t)r0 * CAP + p0] = make_uint2((uint32)s.x, (uint32)t.x);
        if (p1 < CAP) rlist[(size_t)r1 * CAP + p1] = make_uint2((uint32)s.y, (uint32)t.y);
        if (p2 < CAP) rlist[(size_t)r2 * CAP + p2] = make_uint2((uint32)s.z, (uint32)t.z);
        if (p3 < CAP) rlist[(size_t)r3 * CAP + p3] = make_uint2((uint32)s.w, (uint32)t.w);
    }
    if (blk == 0 && tid == 0) {
        for (int e = (E / 4) * 4; e < E; ++e) {
            int t = tgt[e], r = t >> RSH;
            int p = cb[r] + atomicAdd(&cnt[r], 1);
            if (p < CAP) rlist[(size_t)r * CAP + p] = make_uint2((uint32)src[e], (uint32)t);
        }
    }
}

// ---------------------------------------------------------------------------
// K2 (512 threads): blocks < R: per-region CSR build (8x-unrolled passes);
//                   blocks >= R: cvt filler (x f32 -> xb bf16, grid-stride).
// ---------------------------------------------------------------------------
__global__ __launch_bounds__(512)
void csr_cvt_kernel(const uint2* __restrict__ rlist, const int* __restrict__ total,
                    int* __restrict__ start, int* __restrict__ deg,
                    int* __restrict__ csr, int N, int R, int CVB,
                    const float* __restrict__ x, uint4* __restrict__ xb) {
    int blk = blockIdx.x;
    int tid = threadIdx.x;
    if (blk >= R) {   // cvt filler: 8 floats -> 16B bf16 per item
        int n16 = N * 16;
        for (int j = (blk - R) * 512 + tid; j < n16; j += CVB * 512) {
            const float* p = x + (size_t)j * 8;
            float4 a = *(const float4*)p;
            float4 b = *(const float4*)(p + 4);
            uint4 o;
            o.x = pack2(a.x, a.y); o.y = pack2(a.z, a.w);
            o.z = pack2(b.x, b.y); o.w = pack2(b.z, b.w);
            xb[j] = o;
        }
        return;
    }
    __shared__ int lhist[NRG];
    __shared__ int sd[512];
    __shared__ int rbaseSh, countSh;

    int r = blk;
    // rbase = prefix of total over regions < r (256-wide scan)
    if (tid < 256) sd[tid] = (tid < R) ? total[tid] : 0;
    __syncthreads();
    for (int o = 1; o < 256; o <<= 1) {
        int t = (tid >= o && tid < 256) ? sd[tid - o] : 0;
        __syncthreads();
        if (tid < 256) sd[tid] += t;
        __syncthreads();
    }
    if (tid == 0) {
        rbaseSh = (r == 0) ? 0 : sd[r - 1];
        countSh = min(total[r], CAP);
    }
    if (tid < NRG) lhist[tid] = 0;
    __syncthreads();
    int count = countSh;
    const uint2* rl = rlist + (size_t)r * CAP;
    int n0 = r << RSH;

    // pass 1: degree histogram, 8x unrolled
    {
        int i = tid;
        for (; i + 512 * 7 < count; i += 512 * 8) {
            uint2 e0 = rl[i], e1 = rl[i + 512], e2 = rl[i + 1024], e3 = rl[i + 1536];
            uint2 e4 = rl[i + 2048], e5 = rl[i + 2560], e6 = rl[i + 3072], e7 = rl[i + 3584];
            atomicAdd(&lhist[e0.y & (NRG - 1)], 1);
            atomicAdd(&lhist[e1.y & (NRG - 1)], 1);
            atomicAdd(&lhist[e2.y & (NRG - 1)], 1);
            atomicAdd(&lhist[e3.y & (NRG - 1)], 1);
            atomicAdd(&lhist[e4.y & (NRG - 1)], 1);
            atomicAdd(&lhist[e5.y & (NRG - 1)], 1);
            atomicAdd(&lhist[e6.y & (NRG - 1)], 1);
            atomicAdd(&lhist[e7.y & (NRG - 1)], 1);
        }
        for (; i < count; i += 512)
            atomicAdd(&lhist[rl[i].y & (NRG - 1)], 1);
    }
    __syncthreads();

    // exclusive scan of 512 (one element per thread); emit start/deg
    {
        int v = lhist[tid];
        sd[tid] = v;
        __syncthreads();
        for (int o = 1; o < 512; o <<= 1) {
            int t = (tid >= o) ? sd[tid - o] : 0;
            __syncthreads();
            sd[tid] += t;
            __syncthreads();
        }
        int excl = sd[tid] - v + rbaseSh;
        int node = n0 + tid;
        if (node < N) { start[node] = excl; deg[node] = v; }
        lhist[tid] = excl;   // becomes scatter cursor
        __syncthreads();
    }

    // pass 2: scatter into own csr window (~33KB, L2-local), 8x unrolled
    {
        int i = tid;
        for (; i + 512 * 7 < count; i += 512 * 8) {
            uint2 e0 = rl[i], e1 = rl[i + 512], e2 = rl[i + 1024], e3 = rl[i + 1536];
            uint2 e4 = rl[i + 2048], e5 = rl[i + 2560], e6 = rl[i + 3072], e7 = rl[i + 3584];
            int p0 = atomicAdd(&lhist[e0.y & (NRG - 1)], 1);
            int p1 = atomicAdd(&lhist[e1.y & (NRG - 1)], 1);
            int p2 = atomicAdd(&lhist[e2.y & (NRG - 1)], 1);
            int p3 = atomicAdd(&lhist[e3.y & (NRG - 1)], 1);
            int p4 = atomicAdd(&lhist[e4.y & (NRG - 1)], 1);
            int p5 = atomicAdd(&lhist[e5.y & (NRG - 1)], 1);
            int p6 = atomicAdd(&lhist[e6.y & (NRG - 1)], 1);
            int p7 = atomicAdd(&lhist[e7.y & (NRG - 1)], 1);
            csr[p0] = (int)e0.x; csr[p1] = (int)e1.x;
            csr[p2] = (int)e2.x; csr[p3] = (int)e3.x;
            csr[p4] = (int)e4.x; csr[p5] = (int)e5.x;
            csr[p6] = (int)e6.x; csr[p7] = (int)e7.x;
        }
        for (; i < count; i += 512) {
            uint2 e = rl[i];
            int p = atomicAdd(&lhist[e.y & (NRG - 1)], 1);
            csr[p] = (int)e.x;
        }
    }
}

// ---------------------------------------------------------------------------
// agg (R11 verbatim): out = in_t + mean_{s in N(t)} in_s (bf16 in/out).
// One wave per node; 8 edges in flight. No epilogue.
// ---------------------------------------------------------------------------
__global__ __launch_bounds__(256, 4)
void agg_combine_bf16_kernel(const ushort16* __restrict__ hb,
                             const int* __restrict__ startv, const int* __restrict__ degv,
                             const int* __restrict__ csr,
                             uint32* __restrict__ outb, int N) {
    int wid = (blockIdx.x * 256 + threadIdx.x) >> 6;
    int lane = threadIdx.x & 63;
    if (wid >= N) return;
    int g = lane >> 4, sl = lane & 15;
    int s0 = startv[wid];
    int deg = degv[wid];
    int fi = sl * 4 + g;
    uint32 su = ((const uint32*)hb)[(size_t)wid * 64 + fi];

    float acc[8];
#pragma unroll
    for (int j = 0; j < 8; ++j) acc[j] = 0.f;

    int base = 0;
    for (; base + 8 <= deg; base += 8) {
        int i0 = csr[s0 + base + g];
        int i1 = csr[s0 + base + 4 + g];
        uint4 v0 = *(const uint4*)(hb + (size_t)i0 * 128 + sl * 8);
        uint4 v1 = *(const uint4*)(hb + (size_t)i1 * 128 + sl * 8);
        ACC8(v0); ACC8(v1);
    }
    for (; base < deg; base += 4) {
        int e = base + g;
        if (e < deg) {
            int s = csr[s0 + e];
            uint4 v = *(const uint4*)(hb + (size_t)s * 128 + sl * 8);
            ACC8(v);
        }
    }
#pragma unroll
    for (int j = 0; j < 8; ++j) {
        acc[j] += __shfl_xor(acc[j], 16, 64);
        acc[j] += __shfl_xor(acc[j], 32, 64);
    }
    float inv = 1.f / fmaxf((float)deg, 1.f);
    float ax = (g == 0) ? acc[0] : (g == 1) ? acc[2] : (g == 2) ? acc[4] : acc[6];
    float ay = (g == 0) ? acc[1] : (g == 1) ? acc[3] : (g == 2) ? acc[5] : acc[7];
    outb[(size_t)wid * 64 + fi] = pack2(bflo(su) + ax * inv, bfhi(su) + ay * inv);
}

// ---------------------------------------------------------------------------
// GEMM (R11 verbatim): C[M,128] = relu(A[M,128] @ W + b); optional proj path.
// A bf16 row-major; Wt = W^T bf16. Wave = 16 rows, block = 64 rows.
// ---------------------------------------------------------------------------
__global__ __launch_bounds__(256)
void gemm_mfma_kernel(const ushort16* __restrict__ A, const ushort16* __restrict__ Wt,
                      const float* __restrict__ bias, int M,
                      ushort16* __restrict__ outB,
                      const float* __restrict__ Wp, const float* __restrict__ bp,
                      float* __restrict__ outP) {
    const int tid = threadIdx.x;
    const int lane = tid & 63;
    const int wave = tid >> 6;
    const int l15 = lane & 15;
    const int quad = lane >> 4;
    const int r0 = blockIdx.x * 64 + wave * 16;

    int arow = r0 + l15;
    if (arow >= M) arow = M - 1;
    const ushort16* aptr = A + (size_t)arow * 128 + quad * 8;
    short8 afr[4];
#pragma unroll
    for (int kt = 0; kt < 4; ++kt) afr[kt] = ld_frag(aptr + kt * 32);

    f32x4 acc[8];
#pragma unroll
    for (int t = 0; t < 8; ++t) acc[t] = (f32x4){0.f, 0.f, 0.f, 0.f};

#pragma unroll
    for (int t = 0; t < 8; ++t) {
        const ushort16* bptr = Wt + (size_t)(16 * t + l15) * 128 + quad * 8;
        short8 b0 = ld_frag(bptr);
        short8 b1 = ld_frag(bptr + 32);
        short8 b2 = ld_frag(bptr + 64);
        short8 b3 = ld_frag(bptr + 96);
        acc[t] = __builtin_amdgcn_mfma_f32_16x16x32_bf16(afr[0], b0, acc[t], 0, 0, 0);
        acc[t] = __builtin_amdgcn_mfma_f32_16x16x32_bf16(afr[1], b1, acc[t], 0, 0, 0);
        acc[t] = __builtin_amdgcn_mfma_f32_16x16x32_bf16(afr[2], b2, acc[t], 0, 0, 0);
        acc[t] = __builtin_amdgcn_mfma_f32_16x16x32_bf16(afr[3], b3, acc[t], 0, 0, 0);
    }

    if (outP) {
        float p[4][5];
#pragma unroll
        for (int r = 0; r < 4; ++r)
#pragma unroll
            for (int j = 0; j < 5; ++j) p[r][j] = 0.f;
#pragma unroll
        for (int t = 0; t < 8; ++t) {
            float wpl[5];
#pragma unroll
            for (int j = 0; j < 5; ++j) wpl[j] = Wp[(16 * t + l15) * 5 + j];
            float bt = bias[16 * t + l15];
            float ov[4];
            ov[0] = fmaxf(acc[t].x + bt, 0.f);
            ov[1] = fmaxf(acc[t].y + bt, 0.f);
            ov[2] = fmaxf(acc[t].z + bt, 0.f);
            ov[3] = fmaxf(acc[t].w + bt, 0.f);
#pragma unroll
            for (int r = 0; r < 4; ++r)
#pragma unroll
                for (int j = 0; j < 5; ++j) p[r][j] += ov[r] * wpl[j];
        }
#pragma unroll
        for (int m = 1; m <= 8; m <<= 1)
#pragma unroll
            for (int r = 0; r < 4; ++r)
#pragma unroll
                for (int j = 0; j < 5; ++j) p[r][j] += __shfl_xor(p[r][j], m, 64);
        if (l15 == 0) {
#pragma unroll
            for (int r = 0; r < 4; ++r) {
                int row = r0 + quad * 4 + r;
                if (row < M) {
#pragma unroll
                    for (int j = 0; j < 5; ++j) outP[(size_t)row * 5 + j] = p[r][j] + bp[j];
                }
            }
        }
    } else {
#pragma unroll
        for (int t = 0; t < 8; ++t) {
            float bt = bias[16 * t + l15];
            float ov[4];
            ov[0] = fmaxf(acc[t].x + bt, 0.f);
            ov[1] = fmaxf(acc[t].y + bt, 0.f);
            ov[2] = fmaxf(acc[t].z + bt, 0.f);
            ov[3] = fmaxf(acc[t].w + bt, 0.f);
#pragma unroll
            for (int r = 0; r < 4; ++r) {
                float nb = __shfl_xor(ov[r], 1, 64);
                int row = r0 + quad * 4 + r;
                if (((l15 & 1) == 0) && row < M) {
                    *(uint32*)(outB + (size_t)row * 128 + 16 * t + l15) = pack2(ov[r], nb);
                }
            }
        }
    }
}

extern "C" void kernel_launch(void* const* d_in, const int* in_sizes, int n_in,
                              void* d_out, int out_size, void* d_ws, size_t ws_size,
                              hipStream_t stream) {
    const float* x     = (const float*)d_in[0];
    const int*   edges = (const int*)d_in[1];
    const float* W1    = (const float*)d_in[2];
    const float* b1    = (const float*)d_in[3];
    const float* W2    = (const float*)d_in[4];
    const float* b2    = (const float*)d_in[5];
    const float* Wp    = (const float*)d_in[6];
    const float* bp    = (const float*)d_in[7];
    float* out = (float*)d_out;

    int N = in_sizes[0] / 128;   // 100000
    int E = in_sizes[1] / 2;     // 1600000
    const int* src = edges;
    const int* tgt = edges + E;

    const int R  = (N + NRG - 1) >> RSH;     // regions (196)
    const int PB = (E + CH - 1) / CH;        // count/scatter blocks (782)
    const int CVB = 304;                     // cvt filler blocks in K2

    char* ws = (char*)d_ws;
    size_t off = 0;
    auto alloc = [&](size_t bytes) {
        char* p = ws + off;
        off = (off + bytes + 255) & ~(size_t)255;
        return p;
    };
    int*      deg     = (int*)alloc((size_t)N * 4);
    int*      start   = (int*)alloc((size_t)N * 4);
    int*      csr     = (int*)alloc((size_t)E * 4);
    int*      hist    = (int*)alloc((size_t)PB * 256 * 4);
    int*      total   = (int*)alloc(256 * 4);
    ushort16* xb      = (ushort16*)alloc((size_t)N * 128 * 2);
    ushort16* hb1     = (ushort16*)alloc((size_t)N * 128 * 2);
    ushort16* bufAb   = (ushort16*)alloc((size_t)N * 128 * 2);
    ushort16* Wt1     = (ushort16*)alloc(128 * 128 * 2);
    ushort16* Wt2     = (ushort16*)alloc(128 * 128 * 2);
    uint2*    rlist   = (uint2*)bufAb;   // alias: rlist dead before agg1 writes bufAb
    (void)ws_size;

    const int gemmBlocks = (N + 63) / 64;        // 1563
    const int aggBlocks  = (N + 3) / 4;          // 25000

    // K1a: region count + Wt prep
    count_prep_kernel<<<PB + 16, 256, 0, stream>>>(tgt, hist, W1, W2, Wt1, Wt2, E, PB);
    // K1b: per-region column scan -> per-block bases + total
    scan_kernel<<<R, 256, 0, stream>>>(hist, total, PB);
    // K1c: scatter into per-region lists (reserved ranges, no global atomics)
    scatter_kernel<<<PB, 256, 0, stream>>>(src, tgt, hist, rlist, E);
    // K2: per-region CSR build (196 blocks)  ||  cvt x -> xb (304 filler)
    csr_cvt_kernel<<<R + CVB, 512, 0, stream>>>(rlist, total, start, deg, csr,
                                                N, R, CVB, x, (uint4*)xb);
    // K3: agg1 = x + mean_agg(x)  (bf16)
    agg_combine_bf16_kernel<<<aggBlocks, 256, 0, stream>>>(xb, start, deg, csr,
                                                           (uint32*)bufAb, N);
    // K4: h1 = relu(agg1 @ W1 + b1)
    gemm_mfma_kernel<<<gemmBlocks, 256, 0, stream>>>(bufAb, Wt1, b1, N, hb1,
                                                     nullptr, nullptr, nullptr);
    // K5: agg2 = h1 + mean_agg(h1)
    agg_combine_bf16_kernel<<<aggBlocks, 256, 0, stream>>>(hb1, start, deg, csr,
                                                           (uint32*)bufAb, N);
    // K6: out = relu(agg2 @ W2 + b2) @ Wp + bp
    gemm_mfma_kernel<<<gemmBlocks, 256, 0, stream>>>(bufAb, Wt2, b2, N, nullptr,
                                                     Wp, bp, out);
}